// Round 9
// baseline (358.097 us; speedup 1.0000x reference)
//
#include <hip/hip_runtime.h>
#include <hip/hip_bf16.h>
#include <math.h>

typedef unsigned short ushort_t;
typedef unsigned int uint_t;

// Problem constants
#define BB 32
#define PP 6
#define DD 96
#define EE 128
#define HH 8
#define II 64
#define KK 32
#define LSEQ 768            // N*D
#define ROWS (BB * LSEQ)    // 24576 token rows
#define OUTN 128
#define KOUT (LSEQ * EE)    // 98304

using bf16x8 = __attribute__((ext_vector_type(8))) short;
using bf16x4 = __attribute__((ext_vector_type(4))) short;
using f32x4  = __attribute__((ext_vector_type(4))) float;
using u32x4  = __attribute__((ext_vector_type(4))) uint_t;

__device__ __forceinline__ ushort_t f2b(float f) {
    __hip_bfloat16 h = __float2bfloat16(f);
    return *reinterpret_cast<ushort_t*>(&h);
}
// pack two fp32 -> (bf16(hi)<<16)|bf16(lo) by TRUNCATION: one v_perm_b32.
__device__ __forceinline__ uint_t permpack(float hi, float lo) {
    return __builtin_amdgcn_perm(__builtin_bit_cast(uint_t, hi),
                                 __builtin_bit_cast(uint_t, lo), 0x07060302u);
}

// ---------------------------------------------------------------------------
// Cast fp32 -> bf16, all four weight tensors in one launch.
// ---------------------------------------------------------------------------
__global__ void cast_all_kernel(
    const float* __restrict__ s0, int n0, const float* __restrict__ s1, int n1,
    const float* __restrict__ s2, int n2, const float* __restrict__ s3, int n3,
    ushort_t* __restrict__ d0, ushort_t* __restrict__ d1,
    ushort_t* __restrict__ d2, ushort_t* __restrict__ d3)
{
    int i = blockIdx.x * 256 + threadIdx.x;
    if (i < n0) { d0[i] = f2b(s0[i]); return; }
    i -= n0;
    if (i < n1) { d1[i] = f2b(s1[i]); return; }
    i -= n1;
    if (i < n2) { d2[i] = f2b(s2[i]); return; }
    i -= n2;
    if (i < n3) { d3[i] = f2b(s3[i]); }
}

// ---------------------------------------------------------------------------
// Embed (unchanged).
// ---------------------------------------------------------------------------
__global__ __launch_bounds__(128) void embed_kernel(
    const float* __restrict__ x, const float* __restrict__ prot,
    const float* __restrict__ emb_w, const float* __restrict__ emb_b,
    const float* __restrict__ proj_w, const float* __restrict__ proj_b,
    float* __restrict__ seq, ushort_t* __restrict__ seq_bf)
{
    const int r = blockIdx.x;
    const int t = threadIdx.x;
    __shared__ float xrow[PP];
    __shared__ float sel[PP];

    if (t < PP) xrow[t] = x[r * PP + t];
    __syncthreads();

    float nx = 0.f;
    #pragma unroll
    for (int p = 0; p < PP; ++p) nx += xrow[p] * xrow[p];
    const float xinv = 1.f / fmaxf(sqrtf(nx), 1e-12f);

    const int d = r % DD;
    if (t < KK) {
        const float* pr = prot + (d * KK + t) * PP;
        float pp[PP];
        float np2 = 0.f;
        #pragma unroll
        for (int p = 0; p < PP; ++p) { pp[p] = pr[p]; np2 += pp[p] * pp[p]; }
        const float pinv = 1.f / fmaxf(sqrtf(np2), 1e-12f);
        float dot = 0.f;
        #pragma unroll
        for (int p = 0; p < PP; ++p) dot += xrow[p] * pp[p];
        float sim = dot * xinv * pinv;
        int k = t;
        #pragma unroll
        for (int off = 16; off; off >>= 1) {
            float osim = __shfl_down(sim, off);
            int   ok   = __shfl_down(k, off);
            if (osim > sim || (osim == sim && ok < k)) { sim = osim; k = ok; }
        }
        k = __shfl(k, 0);
        if (t == k) {
            #pragma unroll
            for (int p = 0; p < PP; ++p) sel[p] = pp[p] * pinv;
        }
    }
    __syncthreads();

    float acc = emb_b[t] + proj_b[t];
    #pragma unroll
    for (int p = 0; p < PP; ++p) acc = fmaf(xrow[p], emb_w[t * PP + p], acc);
    #pragma unroll
    for (int p = 0; p < PP; ++p) acc = fmaf(sel[p], proj_w[t * PP + p], acc);

    const int lpos = r % LSEQ;
    const float twoj = (float)((t >> 1) * 2);
    const float div = __expf(twoj * (-9.210340371976184f / 128.0f));
    const float ang = (float)lpos * div;
    const float pe = (t & 1) ? cosf(ang) : sinf(ang);
    const float v = acc + pe;
    seq[(size_t)r * EE + t] = v;
    seq_bf[(size_t)r * EE + t] = f2b(v);
}

// ---------------------------------------------------------------------------
// Direct-activation MFMA GEMM (swapped operands) — qkv projection.
// flags: 1 = ELU; 2 = bf16 out; 4 = scale n<128 by 0.25 (Q pre-scale).
// ---------------------------------------------------------------------------
__global__ __launch_bounds__(256) void gemm_direct(
    const ushort_t* __restrict__ A, const ushort_t* __restrict__ W,
    const float* __restrict__ bias, void* __restrict__ Cout,
    int M, int N, int K, int flags)
{
    __shared__ ushort_t Ws[64 * 136];
    const int t = threadIdx.x;
    const int wave = t >> 6, lane = t & 63;
    const int quad = lane >> 4, l16 = lane & 15;
    const int m0 = blockIdx.y * 128, n0 = blockIdx.x * 64;
    const int kp = K + 8;
    const int ak8 = K >> 3;

    for (int c = t; c < 64 * ak8; c += 256) {
        int row = c / ak8, col = c - row * ak8;
        *(bf16x8*)&Ws[row * kp + col * 8] =
            *(const bf16x8*)&W[(size_t)(n0 + row) * K + col * 8];
    }
    __syncthreads();

    f32x4 acc[2][4];
    #pragma unroll
    for (int s = 0; s < 2; ++s)
        #pragma unroll
        for (int nt = 0; nt < 4; ++nt)
            acc[s][nt] = (f32x4){0.f, 0.f, 0.f, 0.f};

    const ushort_t* a0p = A + (size_t)(m0 + wave * 32 + l16) * K + quad * 8;
    const ushort_t* a1p = a0p + (size_t)16 * K;
    const ushort_t* wp  = &Ws[l16 * kp + quad * 8];

    for (int k0 = 0; k0 < K; k0 += 32) {
        bf16x8 a0 = *(const bf16x8*)(a0p + k0);
        bf16x8 a1 = *(const bf16x8*)(a1p + k0);
        #pragma unroll
        for (int nt = 0; nt < 4; ++nt) {
            bf16x8 wf = *(const bf16x8*)(wp + nt * 16 * kp + k0);
            acc[0][nt] = __builtin_amdgcn_mfma_f32_16x16x32_bf16(wf, a0, acc[0][nt], 0, 0, 0);
            acc[1][nt] = __builtin_amdgcn_mfma_f32_16x16x32_bf16(wf, a1, acc[1][nt], 0, 0, 0);
        }
    }

    #pragma unroll
    for (int s = 0; s < 2; ++s) {
        const int m = m0 + wave * 32 + s * 16 + l16;
        #pragma unroll
        for (int nt = 0; nt < 4; ++nt) {
            const int nb = n0 + nt * 16 + quad * 4;
            float4 b4 = *(const float4*)&bias[nb];
            float v[4];
            #pragma unroll
            for (int r = 0; r < 4; ++r) {
                v[r] = acc[s][nt][r] + ((const float*)&b4)[r];
                if (flags & 1) v[r] = v[r] > 0.f ? v[r] : expm1f(v[r]);
            }
            if ((flags & 4) && nb < EE) {
                #pragma unroll
                for (int r = 0; r < 4; ++r) v[r] *= 0.25f;
            }
            if (flags & 2) {
                uint2 w2;
                w2.x = permpack(v[1], v[0]);
                w2.y = permpack(v[3], v[2]);
                *(uint2*)&((ushort_t*)Cout)[(size_t)m * N + nb] = w2;
            } else {
                float4 f4 = {v[0], v[1], v[2], v[3]};
                *(float4*)&((float*)Cout)[(size_t)m * N + nb] = f4;
            }
        }
    }
}

// ---------------------------------------------------------------------------
// MFMA flash attention v6: FULL K preload into registers (48 bf16x4 = 96
// VGPRs) — one up-front load burst instead of 48 latency-exposed loads.
// __launch_bounds__(512,4) caps VGPR at 128 (16 waves/CU).
// ---------------------------------------------------------------------------
#define VTS 792
__global__ __launch_bounds__(512, 4) void attention_mfma(
    const ushort_t* __restrict__ qkv, ushort_t* __restrict__ ctx)
{
    __shared__ ushort_t Vt[16 * VTS];

    const int bh = blockIdx.x;
    const int b = bh & 31, h = bh >> 5;     // XCD swizzle: id%8 == b%8
    const int qb = blockIdx.y * 256;
    const int t = threadIdx.x;
    const int wave = t >> 6, lane = t & 63;
    const int quad = lane >> 4, l16 = lane & 15;
    const size_t bbase = (size_t)b * LSEQ * 384;
    const int hoff = h * 16;

    // ---- stage V transposed ----
    for (int idx = t; idx < 1536; idx += 512) {
        int row = idx >> 1, half = idx & 1;
        bf16x8 v = *(const bf16x8*)&qkv[bbase + (size_t)row * 384 + 2 * EE + hoff + half * 8];
        #pragma unroll
        for (int j = 0; j < 8; ++j)
            Vt[(half * 8 + j) * VTS + row] = (ushort_t)v[j];
    }

    // ---- preload ALL K fragments (burst; latency paid once) ----
    const ushort_t* kbase = qkv + bbase + EE + hoff + quad * 4;
    bf16x4 kreg[48];
    #pragma unroll
    for (int c = 0; c < 48; ++c)
        kreg[c] = *(const bf16x4*)&kbase[(size_t)(c * 16 + l16) * 384];

    // ---- Q fragments ----
    bf16x4 qf[2];
    #pragma unroll
    for (int s = 0; s < 2; ++s) {
        int row = qb + wave * 32 + s * 16 + l16;
        qf[s] = *(const bf16x4*)&qkv[bbase + (size_t)row * 384 + hoff + quad * 4];
    }
    __syncthreads();

    f32x4 oacc[2];
    oacc[0] = (f32x4){0.f, 0.f, 0.f, 0.f};
    oacc[1] = (f32x4){0.f, 0.f, 0.f, 0.f};
    float lsum[2] = {0.f, 0.f};
    const f32x4 zero4 = (f32x4){0.f, 0.f, 0.f, 0.f};

    #pragma unroll
    for (int c = 0; c < 48; ++c) {
        bf16x4 vf = *(const bf16x4*)&Vt[l16 * VTS + c * 16 + quad * 4];
        #pragma unroll
        for (int s = 0; s < 2; ++s) {
            f32x4 sv = __builtin_amdgcn_mfma_f32_16x16x16bf16_1k(kreg[c], qf[s], zero4, 0, 0, 0);
            float e0 = __expf(sv[0]), e1 = __expf(sv[1]);
            float e2 = __expf(sv[2]), e3 = __expf(sv[3]);
            lsum[s] += (e0 + e1) + (e2 + e3);
            uint2 pu;
            pu.x = permpack(e1, e0);
            pu.y = permpack(e3, e2);
            bf16x4 pf = __builtin_bit_cast(bf16x4, pu);
            oacc[s] = __builtin_amdgcn_mfma_f32_16x16x16bf16_1k(vf, pf, oacc[s], 0, 0, 0);
        }
    }

    #pragma unroll
    for (int s = 0; s < 2; ++s) {
        float tot = lsum[s];
        tot += __shfl_xor(tot, 16);
        tot += __shfl_xor(tot, 32);
        const float inv = 1.f / tot;
        const int q = qb + wave * 32 + s * 16 + l16;
        uint2 w2;
        w2.x = permpack(oacc[s][1] * inv, oacc[s][0] * inv);
        w2.y = permpack(oacc[s][3] * inv, oacc[s][2] * inv);
        *(uint2*)&ctx[((size_t)(b * LSEQ + q)) * EE + hoff + quad * 4] = w2;
    }
}

// ---------------------------------------------------------------------------
// Fused layer tail: seq = LN2(y + FFN(y)), y = LN1(seq + ctx@Wout^T + bout).
// One kernel, NO barriers:
//  - All weights read DIRECTLY from global (Wout 32K + W1 16K + W2 16K are
//    L1-resident; every block reads the same tables).
//  - LN1 output y parked in wave-private LDS rows (Ys) for FFN1 A-frags;
//    write->read is same-wave, compiler's lgkmcnt waits suffice.
//  - y kept in registers = FFN2's residual (same lane positions by C-layout).
// Block = 64 rows (4 independent waves x 16 rows). LDS: Ys 17.4K + Hs 9.2K.
// ---------------------------------------------------------------------------
__global__ __launch_bounds__(256) void layer_tail(
    const ushort_t* __restrict__ ctx, const ushort_t* __restrict__ Wout,
    const float* __restrict__ bout,
    const ushort_t* __restrict__ W1, const float* __restrict__ b1,
    const ushort_t* __restrict__ W2, const float* __restrict__ b2,
    const float* __restrict__ g1, const float* __restrict__ be1,
    const float* __restrict__ g2, const float* __restrict__ be2,
    float* __restrict__ seq, ushort_t* __restrict__ seq_bf)
{
    __shared__ ushort_t Ys[64 * 136];
    __shared__ ushort_t Hs[64 * 72];
    const int t = threadIdx.x;
    const int wave = t >> 6, lane = t & 63;
    const int quad = lane >> 4, l16 = lane & 15;
    const int lrow = wave * 16 + l16;
    const int m = blockIdx.x * 64 + lrow;

    // ---- out-proj GEMM: attn_out = ctx @ Wout^T ----
    f32x4 acc[8];
    #pragma unroll
    for (int nt = 0; nt < 8; ++nt) acc[nt] = (f32x4){0.f, 0.f, 0.f, 0.f};
    const ushort_t* ap = ctx + (size_t)m * EE + quad * 8;
    const ushort_t* wp = Wout + (size_t)l16 * EE + quad * 8;
    #pragma unroll
    for (int k0 = 0; k0 < 128; k0 += 32) {
        bf16x8 a = *(const bf16x8*)(ap + k0);
        #pragma unroll
        for (int nt = 0; nt < 8; ++nt) {
            bf16x8 wf = *(const bf16x8*)(wp + (size_t)nt * 16 * EE + k0);
            acc[nt] = __builtin_amdgcn_mfma_f32_16x16x32_bf16(wf, a, acc[nt], 0, 0, 0);
        }
    }

    // ---- LN1: y = LN(seq + attn_out + bout)*g1 + be1 (regs + Ys LDS) ----
    float y[8][4];
    float s = 0.f;
    #pragma unroll
    for (int nt = 0; nt < 8; ++nt) {
        const int nb = nt * 16 + quad * 4;
        float4 b4 = *(const float4*)&bout[nb];
        float4 r4 = *(const float4*)&seq[(size_t)m * EE + nb];
        #pragma unroll
        for (int r = 0; r < 4; ++r) {
            y[nt][r] = acc[nt][r] + ((const float*)&b4)[r] + ((const float*)&r4)[r];
            s += y[nt][r];
        }
    }
    s += __shfl_xor(s, 16);
    s += __shfl_xor(s, 32);
    const float mean1 = s * (1.f / 128.f);
    float s2 = 0.f;
    #pragma unroll
    for (int nt = 0; nt < 8; ++nt)
        #pragma unroll
        for (int r = 0; r < 4; ++r) {
            float d = y[nt][r] - mean1;
            s2 += d * d;
        }
    s2 += __shfl_xor(s2, 16);
    s2 += __shfl_xor(s2, 32);
    const float rstd1 = 1.f / sqrtf(s2 * (1.f / 128.f) + 1e-5f);
    #pragma unroll
    for (int nt = 0; nt < 8; ++nt) {
        const int nb = nt * 16 + quad * 4;
        float4 g4 = *(const float4*)&g1[nb];
        float4 be4 = *(const float4*)&be1[nb];
        #pragma unroll
        for (int r = 0; r < 4; ++r)
            y[nt][r] = (y[nt][r] - mean1) * rstd1 * ((const float*)&g4)[r] + ((const float*)&be4)[r];
        uint2 w2;
        w2.x = permpack(y[nt][1], y[nt][0]);
        w2.y = permpack(y[nt][3], y[nt][2]);
        *(uint2*)&Ys[lrow * 136 + nb] = w2;     // wave-private row
    }

    // ---- FFN1: h = elu(y @ W1^T + b1) ----
    f32x4 acc1[4];
    #pragma unroll
    for (int nt = 0; nt < 4; ++nt) acc1[nt] = (f32x4){0.f, 0.f, 0.f, 0.f};
    const ushort_t* yp = &Ys[lrow * 136 + quad * 8];
    const ushort_t* w1p = W1 + (size_t)l16 * EE + quad * 8;
    #pragma unroll
    for (int k0 = 0; k0 < 128; k0 += 32) {
        bf16x8 a = *(const bf16x8*)(yp + k0);
        #pragma unroll
        for (int nt = 0; nt < 4; ++nt) {
            bf16x8 wf = *(const bf16x8*)(w1p + (size_t)nt * 16 * EE + k0);
            acc1[nt] = __builtin_amdgcn_mfma_f32_16x16x32_bf16(wf, a, acc1[nt], 0, 0, 0);
        }
    }
    #pragma unroll
    for (int nt = 0; nt < 4; ++nt) {
        const int ib = nt * 16 + quad * 4;
        float4 b4 = *(const float4*)&b1[ib];
        float hv[4];
        #pragma unroll
        for (int r = 0; r < 4; ++r) {
            float u = acc1[nt][r] + ((const float*)&b4)[r];
            hv[r] = u > 0.f ? u : expm1f(u);
        }
        uint2 w2;
        w2.x = permpack(hv[1], hv[0]);
        w2.y = permpack(hv[3], hv[2]);
        *(uint2*)&Hs[lrow * 72 + ib] = w2;      // wave-private row
    }

    // ---- FFN2: ffn_out = h @ W2^T ----
    f32x4 acc2[8];
    #pragma unroll
    for (int nt = 0; nt < 8; ++nt) acc2[nt] = (f32x4){0.f, 0.f, 0.f, 0.f};
    const ushort_t* hp = &Hs[lrow * 72 + quad * 8];
    const ushort_t* w2p = W2 + (size_t)l16 * II + quad * 8;
    #pragma unroll
    for (int k0 = 0; k0 < 64; k0 += 32) {
        bf16x8 hf = *(const bf16x8*)(hp + k0);
        #pragma unroll
        for (int nt = 0; nt < 8; ++nt) {
            bf16x8 wf = *(const bf16x8*)(w2p + (size_t)nt * 16 * II + k0);
            acc2[nt] = __builtin_amdgcn_mfma_f32_16x16x32_bf16(wf, hf, acc2[nt], 0, 0, 0);
        }
    }

    // ---- LN2: seq = LN(y + ffn_out + b2)*g2 + be2 ----
    float v[8][4];
    float s3 = 0.f;
    #pragma unroll
    for (int nt = 0; nt < 8; ++nt) {
        const int nb = nt * 16 + quad * 4;
        float4 b4 = *(const float4*)&b2[nb];
        #pragma unroll
        for (int r = 0; r < 4; ++r) {
            v[nt][r] = acc2[nt][r] + ((const float*)&b4)[r] + y[nt][r];
            s3 += v[nt][r];
        }
    }
    s3 += __shfl_xor(s3, 16);
    s3 += __shfl_xor(s3, 32);
    const float mean2 = s3 * (1.f / 128.f);
    float s4 = 0.f;
    #pragma unroll
    for (int nt = 0; nt < 8; ++nt)
        #pragma unroll
        for (int r = 0; r < 4; ++r) {
            float d = v[nt][r] - mean2;
            s4 += d * d;
        }
    s4 += __shfl_xor(s4, 16);
    s4 += __shfl_xor(s4, 32);
    const float rstd2 = 1.f / sqrtf(s4 * (1.f / 128.f) + 1e-5f);
    #pragma unroll
    for (int nt = 0; nt < 8; ++nt) {
        const int nb = nt * 16 + quad * 4;
        float4 g4 = *(const float4*)&g2[nb];
        float4 be4 = *(const float4*)&be2[nb];
        float out4[4];
        #pragma unroll
        for (int r = 0; r < 4; ++r)
            out4[r] = (v[nt][r] - mean2) * rstd2 * ((const float*)&g4)[r] + ((const float*)&be4)[r];
        float4 f4 = {out4[0], out4[1], out4[2], out4[3]};
        *(float4*)&seq[(size_t)m * EE + nb] = f4;
        uint2 w2;
        w2.x = permpack(out4[1], out4[0]);
        w2.y = permpack(out4[3], out4[2]);
        *(uint2*)&seq_bf[(size_t)m * EE + nb] = w2;
    }
}

// ---------------------------------------------------------------------------
// Final projection, split-K MFMA (unchanged).
// ---------------------------------------------------------------------------
#define PKC 192
#define PNBLK (KOUT / PKC)   // 512
__global__ __launch_bounds__(256) void out_gemm3(
    const ushort_t* __restrict__ seqbf, const float* __restrict__ out_w,
    float* __restrict__ part)
{
    const int t = threadIdx.x;
    const int wave = t >> 6, lane = t & 63;
    const int quad = lane >> 4, l16 = lane & 15;
    const size_t k0 = (size_t)blockIdx.x * PKC;
    const int n0 = wave * 32;

    f32x4 acc[2][2];
    #pragma unroll
    for (int mt = 0; mt < 2; ++mt)
        #pragma unroll
        for (int nt = 0; nt < 2; ++nt)
            acc[mt][nt] = (f32x4){0.f, 0.f, 0.f, 0.f};

    const ushort_t* a0p = seqbf + (size_t)l16 * KOUT + k0 + quad * 8;
    const ushort_t* a1p = a0p + (size_t)16 * KOUT;
    const float* w0p = out_w + (size_t)(n0 + l16) * KOUT + k0 + quad * 8;
    const float* w1p = w0p + (size_t)16 * KOUT;

    #pragma unroll
    for (int ks = 0; ks < PKC; ks += 32) {
        bf16x8 a0 = *(const bf16x8*)(a0p + ks);
        bf16x8 a1 = *(const bf16x8*)(a1p + ks);
        float4 wa0 = *(const float4*)(w0p + ks);
        float4 wa1 = *(const float4*)(w0p + ks + 4);
        float4 wb0 = *(const float4*)(w1p + ks);
        float4 wb1 = *(const float4*)(w1p + ks + 4);
        u32x4 b0, b1;
        b0[0] = permpack(wa0.y, wa0.x); b0[1] = permpack(wa0.w, wa0.z);
        b0[2] = permpack(wa1.y, wa1.x); b0[3] = permpack(wa1.w, wa1.z);
        b1[0] = permpack(wb0.y, wb0.x); b1[1] = permpack(wb0.w, wb0.z);
        b1[2] = permpack(wb1.y, wb1.x); b1[3] = permpack(wb1.w, wb1.z);
        bf16x8 bf0 = __builtin_bit_cast(bf16x8, b0);
        bf16x8 bf1 = __builtin_bit_cast(bf16x8, b1);
        acc[0][0] = __builtin_amdgcn_mfma_f32_16x16x32_bf16(a0, bf0, acc[0][0], 0, 0, 0);
        acc[1][0] = __builtin_amdgcn_mfma_f32_16x16x32_bf16(a1, bf0, acc[1][0], 0, 0, 0);
        acc[0][1] = __builtin_amdgcn_mfma_f32_16x16x32_bf16(a0, bf1, acc[0][1], 0, 0, 0);
        acc[1][1] = __builtin_amdgcn_mfma_f32_16x16x32_bf16(a1, bf1, acc[1][1], 0, 0, 0);
    }

    float* pb = part + (size_t)blockIdx.x * (32 * 128);
    #pragma unroll
    for (int mt = 0; mt < 2; ++mt)
        #pragma unroll
        for (int nt = 0; nt < 2; ++nt)
            #pragma unroll
            for (int r = 0; r < 4; ++r)
                pb[(mt * 16 + quad * 4 + r) * 128 + n0 + nt * 16 + l16] = acc[mt][nt][r];
}

__global__ __launch_bounds__(256) void out_reduce(
    const float* __restrict__ part, const float* __restrict__ out_b,
    float* __restrict__ out)
{
    const int i = blockIdx.x * 256 + threadIdx.x;
    const float* p = part + i;
    float s0 = 0.f, s1 = 0.f, s2 = 0.f, s3 = 0.f;
    for (int blk = 0; blk < PNBLK; blk += 4) {
        s0 += p[(size_t)blk * 4096];
        s1 += p[(size_t)(blk + 1) * 4096];
        s2 += p[(size_t)(blk + 2) * 4096];
        s3 += p[(size_t)(blk + 3) * 4096];
    }
    out[i] = out_b[i & (OUTN - 1)] + ((s0 + s1) + (s2 + s3));
}

// ---------------------------------------------------------------------------
extern "C" void kernel_launch(void* const* d_in, const int* in_sizes, int n_in,
                              void* d_out, int out_size, void* d_ws, size_t ws_size,
                              hipStream_t stream)
{
    const float* x          = (const float*)d_in[0];
    const float* prototypes = (const float*)d_in[1];
    const float* emb_w      = (const float*)d_in[2];
    const float* emb_b      = (const float*)d_in[3];
    const float* proj_w     = (const float*)d_in[4];
    const float* proj_b     = (const float*)d_in[5];
    const float* in_proj_w  = (const float*)d_in[6];
    const float* in_proj_b  = (const float*)d_in[7];
    const float* out_proj_w = (const float*)d_in[8];
    const float* out_proj_b = (const float*)d_in[9];
    const float* ln1_s      = (const float*)d_in[10];
    const float* ln1_b      = (const float*)d_in[11];
    const float* ffn_w1     = (const float*)d_in[12];
    const float* ffn_b1     = (const float*)d_in[13];
    const float* ffn_w2     = (const float*)d_in[14];
    const float* ffn_b2     = (const float*)d_in[15];
    const float* ln2_s      = (const float*)d_in[16];
    const float* ln2_b      = (const float*)d_in[17];
    const float* out_w      = (const float*)d_in[18];
    const float* out_b      = (const float*)d_in[19];
    float* out = (float*)d_out;
    char* base = (char*)d_ws;

    float*    seq    = (float*)base;                        // 12,582,912
    float*    tmp    = (float*)(base + 12582912);           // 12,582,912 (= part)
    ushort_t* seq_bf = (ushort_t*)(base + 25165824);        //  6,291,456
    ushort_t* qkv_bf = (ushort_t*)(base + 31457280);        // 18,874,368
    ushort_t* ctx_bf = (ushort_t*)(base + 50331648);        //  6,291,456
    ushort_t* w_bf   = (ushort_t*)(base + 56623104);        //    327,680
    float*    part   = tmp;
    (void)ws_size;

    ushort_t* w_in  = w_bf;            // [2][384][128]
    ushort_t* w_out = w_bf + 98304;    // [2][128][128]
    ushort_t* w_f1  = w_bf + 131072;   // [2][64][128]
    ushort_t* w_f2  = w_bf + 147456;   // [2][128][64]

    cast_all_kernel<<<(163840 + 255) / 256, 256, 0, stream>>>(
        in_proj_w, 98304, out_proj_w, 32768, ffn_w1, 16384, ffn_w2, 16384,
        w_in, w_out, w_f1, w_f2);

    embed_kernel<<<ROWS, 128, 0, stream>>>(x, prototypes, emb_w, emb_b,
                                           proj_w, proj_b, seq, seq_bf);

    for (int l = 0; l < 2; ++l) {
        // qkv = seq @ Wqkv^T + b -> bf16 [24576, 384], Q cols pre-scaled 0.25
        gemm_direct<<<dim3(6, 192), 256, 0, stream>>>(
            seq_bf, w_in + (size_t)l * 49152, in_proj_b + l * 384,
            qkv_bf, ROWS, 384, 128, 2 | 4);
        attention_mfma<<<dim3(BB * HH, 3), 512, 0, stream>>>(qkv_bf, ctx_bf);
        // whole layer tail in one kernel (out-proj + LN1 + FFN + LN2)
        layer_tail<<<ROWS / 64, 256, 0, stream>>>(
            ctx_bf, w_out + (size_t)l * 16384, out_proj_b + l * 128,
            w_f1 + (size_t)l * 8192, ffn_b1 + l * II,
            w_f2 + (size_t)l * 8192, ffn_b2 + l * EE,
            ln1_s + l * EE, ln1_b + l * EE, ln2_s + l * EE, ln2_b + l * EE,
            seq, seq_bf);
    }

    out_gemm3<<<PNBLK, 256, 0, stream>>>(seq_bf, out_w, part);
    out_reduce<<<BB * OUTN / 256, 256, 0, stream>>>(part, out_b, out);
}

// Round 10
// 344.739 us; speedup vs baseline: 1.0387x; 1.0387x over previous
//
#include <hip/hip_runtime.h>
#include <hip/hip_bf16.h>
#include <math.h>

typedef unsigned short ushort_t;
typedef unsigned int uint_t;

// Problem constants
#define BB 32
#define PP 6
#define DD 96
#define EE 128
#define HH 8
#define II 64
#define KK 32
#define LSEQ 768            // N*D
#define ROWS (BB * LSEQ)    // 24576 token rows
#define OUTN 128
#define KOUT (LSEQ * EE)    // 98304

using bf16x8 = __attribute__((ext_vector_type(8))) short;
using bf16x4 = __attribute__((ext_vector_type(4))) short;
using f32x4  = __attribute__((ext_vector_type(4))) float;
using u32x4  = __attribute__((ext_vector_type(4))) uint_t;

__device__ __forceinline__ ushort_t f2b(float f) {
    __hip_bfloat16 h = __float2bfloat16(f);
    return *reinterpret_cast<ushort_t*>(&h);
}
// pack two fp32 -> (bf16(hi)<<16)|bf16(lo) by TRUNCATION: one v_perm_b32.
__device__ __forceinline__ uint_t permpack(float hi, float lo) {
    return __builtin_amdgcn_perm(__builtin_bit_cast(uint_t, hi),
                                 __builtin_bit_cast(uint_t, lo), 0x07060302u);
}

// ---------------------------------------------------------------------------
// Cast fp32 -> bf16, all four weight tensors in one launch.
// ---------------------------------------------------------------------------
__global__ void cast_all_kernel(
    const float* __restrict__ s0, int n0, const float* __restrict__ s1, int n1,
    const float* __restrict__ s2, int n2, const float* __restrict__ s3, int n3,
    ushort_t* __restrict__ d0, ushort_t* __restrict__ d1,
    ushort_t* __restrict__ d2, ushort_t* __restrict__ d3)
{
    int i = blockIdx.x * 256 + threadIdx.x;
    if (i < n0) { d0[i] = f2b(s0[i]); return; }
    i -= n0;
    if (i < n1) { d1[i] = f2b(s1[i]); return; }
    i -= n1;
    if (i < n2) { d2[i] = f2b(s2[i]); return; }
    i -= n2;
    if (i < n3) { d3[i] = f2b(s3[i]); }
}

// ---------------------------------------------------------------------------
// Embed (unchanged).
// ---------------------------------------------------------------------------
__global__ __launch_bounds__(128) void embed_kernel(
    const float* __restrict__ x, const float* __restrict__ prot,
    const float* __restrict__ emb_w, const float* __restrict__ emb_b,
    const float* __restrict__ proj_w, const float* __restrict__ proj_b,
    float* __restrict__ seq, ushort_t* __restrict__ seq_bf)
{
    const int r = blockIdx.x;
    const int t = threadIdx.x;
    __shared__ float xrow[PP];
    __shared__ float sel[PP];

    if (t < PP) xrow[t] = x[r * PP + t];
    __syncthreads();

    float nx = 0.f;
    #pragma unroll
    for (int p = 0; p < PP; ++p) nx += xrow[p] * xrow[p];
    const float xinv = 1.f / fmaxf(sqrtf(nx), 1e-12f);

    const int d = r % DD;
    if (t < KK) {
        const float* pr = prot + (d * KK + t) * PP;
        float pp[PP];
        float np2 = 0.f;
        #pragma unroll
        for (int p = 0; p < PP; ++p) { pp[p] = pr[p]; np2 += pp[p] * pp[p]; }
        const float pinv = 1.f / fmaxf(sqrtf(np2), 1e-12f);
        float dot = 0.f;
        #pragma unroll
        for (int p = 0; p < PP; ++p) dot += xrow[p] * pp[p];
        float sim = dot * xinv * pinv;
        int k = t;
        #pragma unroll
        for (int off = 16; off; off >>= 1) {
            float osim = __shfl_down(sim, off);
            int   ok   = __shfl_down(k, off);
            if (osim > sim || (osim == sim && ok < k)) { sim = osim; k = ok; }
        }
        k = __shfl(k, 0);
        if (t == k) {
            #pragma unroll
            for (int p = 0; p < PP; ++p) sel[p] = pp[p] * pinv;
        }
    }
    __syncthreads();

    float acc = emb_b[t] + proj_b[t];
    #pragma unroll
    for (int p = 0; p < PP; ++p) acc = fmaf(xrow[p], emb_w[t * PP + p], acc);
    #pragma unroll
    for (int p = 0; p < PP; ++p) acc = fmaf(sel[p], proj_w[t * PP + p], acc);

    const int lpos = r % LSEQ;
    const float twoj = (float)((t >> 1) * 2);
    const float div = __expf(twoj * (-9.210340371976184f / 128.0f));
    const float ang = (float)lpos * div;
    const float pe = (t & 1) ? cosf(ang) : sinf(ang);
    const float v = acc + pe;
    seq[(size_t)r * EE + t] = v;
    seq_bf[(size_t)r * EE + t] = f2b(v);
}

// ---------------------------------------------------------------------------
// Direct-activation MFMA GEMM (swapped operands) — qkv projection.
// flags: 1 = ELU; 2 = bf16 out; 4 = scale n<128 by 0.25 (Q pre-scale).
// ---------------------------------------------------------------------------
__global__ __launch_bounds__(256) void gemm_direct(
    const ushort_t* __restrict__ A, const ushort_t* __restrict__ W,
    const float* __restrict__ bias, void* __restrict__ Cout,
    int M, int N, int K, int flags)
{
    __shared__ ushort_t Ws[64 * 136];
    const int t = threadIdx.x;
    const int wave = t >> 6, lane = t & 63;
    const int quad = lane >> 4, l16 = lane & 15;
    const int m0 = blockIdx.y * 128, n0 = blockIdx.x * 64;
    const int kp = K + 8;
    const int ak8 = K >> 3;

    for (int c = t; c < 64 * ak8; c += 256) {
        int row = c / ak8, col = c - row * ak8;
        *(bf16x8*)&Ws[row * kp + col * 8] =
            *(const bf16x8*)&W[(size_t)(n0 + row) * K + col * 8];
    }
    __syncthreads();

    f32x4 acc[2][4];
    #pragma unroll
    for (int s = 0; s < 2; ++s)
        #pragma unroll
        for (int nt = 0; nt < 4; ++nt)
            acc[s][nt] = (f32x4){0.f, 0.f, 0.f, 0.f};

    const ushort_t* a0p = A + (size_t)(m0 + wave * 32 + l16) * K + quad * 8;
    const ushort_t* a1p = a0p + (size_t)16 * K;
    const ushort_t* wp  = &Ws[l16 * kp + quad * 8];

    for (int k0 = 0; k0 < K; k0 += 32) {
        bf16x8 a0 = *(const bf16x8*)(a0p + k0);
        bf16x8 a1 = *(const bf16x8*)(a1p + k0);
        #pragma unroll
        for (int nt = 0; nt < 4; ++nt) {
            bf16x8 wf = *(const bf16x8*)(wp + nt * 16 * kp + k0);
            acc[0][nt] = __builtin_amdgcn_mfma_f32_16x16x32_bf16(wf, a0, acc[0][nt], 0, 0, 0);
            acc[1][nt] = __builtin_amdgcn_mfma_f32_16x16x32_bf16(wf, a1, acc[1][nt], 0, 0, 0);
        }
    }

    #pragma unroll
    for (int s = 0; s < 2; ++s) {
        const int m = m0 + wave * 32 + s * 16 + l16;
        #pragma unroll
        for (int nt = 0; nt < 4; ++nt) {
            const int nb = n0 + nt * 16 + quad * 4;
            float4 b4 = *(const float4*)&bias[nb];
            float v[4];
            #pragma unroll
            for (int r = 0; r < 4; ++r) {
                v[r] = acc[s][nt][r] + ((const float*)&b4)[r];
                if (flags & 1) v[r] = v[r] > 0.f ? v[r] : expm1f(v[r]);
            }
            if ((flags & 4) && nb < EE) {
                #pragma unroll
                for (int r = 0; r < 4; ++r) v[r] *= 0.25f;
            }
            if (flags & 2) {
                uint2 w2;
                w2.x = permpack(v[1], v[0]);
                w2.y = permpack(v[3], v[2]);
                *(uint2*)&((ushort_t*)Cout)[(size_t)m * N + nb] = w2;
            } else {
                float4 f4 = {v[0], v[1], v[2], v[3]};
                *(float4*)&((float*)Cout)[(size_t)m * N + nb] = f4;
            }
        }
    }
}

// ---------------------------------------------------------------------------
// MFMA flash attention v7: round-8 structure (VGPR~20, occ~55%) + depth-3
// K prefetch ring (loads issue ~3x80 cyc ahead -> covers ~200 cyc L2 latency)
// + VTS=796 (dword stride 398 == 14 mod 32: 16 distinct banks across l16,
// rows 8B-aligned). NO launch_bounds VGPR cap (round-9 lesson: (512,4)
// forced 64 VGPR and killed occupancy).
// ---------------------------------------------------------------------------
#define VTS 796
__global__ __launch_bounds__(512) void attention_mfma(
    const ushort_t* __restrict__ qkv, ushort_t* __restrict__ ctx)
{
    __shared__ ushort_t Vt[16 * VTS];

    const int bh = blockIdx.x;
    const int b = bh & 31, h = bh >> 5;     // XCD swizzle: id%8 == b%8
    const int qb = blockIdx.y * 256;
    const int t = threadIdx.x;
    const int wave = t >> 6, lane = t & 63;
    const int quad = lane >> 4, l16 = lane & 15;
    const size_t bbase = (size_t)b * LSEQ * 384;
    const int hoff = h * 16;

    // ---- stage V transposed ----
    for (int idx = t; idx < 1536; idx += 512) {
        int row = idx >> 1, half = idx & 1;
        bf16x8 v = *(const bf16x8*)&qkv[bbase + (size_t)row * 384 + 2 * EE + hoff + half * 8];
        #pragma unroll
        for (int j = 0; j < 8; ++j)
            Vt[(half * 8 + j) * VTS + row] = (ushort_t)v[j];
    }

    // ---- Q fragments ----
    bf16x4 qf[2];
    #pragma unroll
    for (int s = 0; s < 2; ++s) {
        int row = qb + wave * 32 + s * 16 + l16;
        qf[s] = *(const bf16x4*)&qkv[bbase + (size_t)row * 384 + hoff + quad * 4];
    }
    __syncthreads();

    f32x4 oacc[2];
    oacc[0] = (f32x4){0.f, 0.f, 0.f, 0.f};
    oacc[1] = (f32x4){0.f, 0.f, 0.f, 0.f};
    float lsum[2] = {0.f, 0.f};
    const f32x4 zero4 = (f32x4){0.f, 0.f, 0.f, 0.f};

    const ushort_t* kbase = qkv + bbase + EE + hoff + quad * 4 + (size_t)l16 * 384;

    // depth-3 prefetch ring (each chunk = 16 key rows = 16*384 elements)
    bf16x4 kr0 = *(const bf16x4*)&kbase[0];
    bf16x4 kr1 = *(const bf16x4*)&kbase[16 * 384];
    bf16x4 kr2 = *(const bf16x4*)&kbase[2 * 16 * 384];

    for (int c = 0; c < 48; ++c) {
        bf16x4 kcur = kr0;
        kr0 = kr1;
        kr1 = kr2;
        const int cn = (c + 3 < 48) ? c + 3 : 47;      // unconditional issue
        kr2 = *(const bf16x4*)&kbase[(size_t)cn * 16 * 384];

        bf16x4 vf = *(const bf16x4*)&Vt[l16 * VTS + c * 16 + quad * 4];

        #pragma unroll
        for (int s = 0; s < 2; ++s) {
            f32x4 sv = __builtin_amdgcn_mfma_f32_16x16x16bf16_1k(kcur, qf[s], zero4, 0, 0, 0);
            float e0 = __expf(sv[0]), e1 = __expf(sv[1]);
            float e2 = __expf(sv[2]), e3 = __expf(sv[3]);
            lsum[s] += (e0 + e1) + (e2 + e3);
            uint2 pu;
            pu.x = permpack(e1, e0);
            pu.y = permpack(e3, e2);
            bf16x4 pf = __builtin_bit_cast(bf16x4, pu);
            oacc[s] = __builtin_amdgcn_mfma_f32_16x16x16bf16_1k(vf, pf, oacc[s], 0, 0, 0);
        }
    }

    #pragma unroll
    for (int s = 0; s < 2; ++s) {
        float tot = lsum[s];
        tot += __shfl_xor(tot, 16);
        tot += __shfl_xor(tot, 32);
        const float inv = 1.f / tot;
        const int q = qb + wave * 32 + s * 16 + l16;
        uint2 w2;
        w2.x = permpack(oacc[s][1] * inv, oacc[s][0] * inv);
        w2.y = permpack(oacc[s][3] * inv, oacc[s][2] * inv);
        *(uint2*)&ctx[((size_t)(b * LSEQ + q)) * EE + hoff + quad * 4] = w2;
    }
}

// ---------------------------------------------------------------------------
// Fused layer tail: seq = LN2(y + FFN(y)), y = LN1(seq + ctx@Wout^T + bout).
// (unchanged from round 9)
// ---------------------------------------------------------------------------
__global__ __launch_bounds__(256) void layer_tail(
    const ushort_t* __restrict__ ctx, const ushort_t* __restrict__ Wout,
    const float* __restrict__ bout,
    const ushort_t* __restrict__ W1, const float* __restrict__ b1,
    const ushort_t* __restrict__ W2, const float* __restrict__ b2,
    const float* __restrict__ g1, const float* __restrict__ be1,
    const float* __restrict__ g2, const float* __restrict__ be2,
    float* __restrict__ seq, ushort_t* __restrict__ seq_bf)
{
    __shared__ ushort_t Ys[64 * 136];
    __shared__ ushort_t Hs[64 * 72];
    const int t = threadIdx.x;
    const int wave = t >> 6, lane = t & 63;
    const int quad = lane >> 4, l16 = lane & 15;
    const int lrow = wave * 16 + l16;
    const int m = blockIdx.x * 64 + lrow;

    // ---- out-proj GEMM: attn_out = ctx @ Wout^T ----
    f32x4 acc[8];
    #pragma unroll
    for (int nt = 0; nt < 8; ++nt) acc[nt] = (f32x4){0.f, 0.f, 0.f, 0.f};
    const ushort_t* ap = ctx + (size_t)m * EE + quad * 8;
    const ushort_t* wp = Wout + (size_t)l16 * EE + quad * 8;
    #pragma unroll
    for (int k0 = 0; k0 < 128; k0 += 32) {
        bf16x8 a = *(const bf16x8*)(ap + k0);
        #pragma unroll
        for (int nt = 0; nt < 8; ++nt) {
            bf16x8 wf = *(const bf16x8*)(wp + (size_t)nt * 16 * EE + k0);
            acc[nt] = __builtin_amdgcn_mfma_f32_16x16x32_bf16(wf, a, acc[nt], 0, 0, 0);
        }
    }

    // ---- LN1 ----
    float y[8][4];
    float s = 0.f;
    #pragma unroll
    for (int nt = 0; nt < 8; ++nt) {
        const int nb = nt * 16 + quad * 4;
        float4 b4 = *(const float4*)&bout[nb];
        float4 r4 = *(const float4*)&seq[(size_t)m * EE + nb];
        #pragma unroll
        for (int r = 0; r < 4; ++r) {
            y[nt][r] = acc[nt][r] + ((const float*)&b4)[r] + ((const float*)&r4)[r];
            s += y[nt][r];
        }
    }
    s += __shfl_xor(s, 16);
    s += __shfl_xor(s, 32);
    const float mean1 = s * (1.f / 128.f);
    float s2 = 0.f;
    #pragma unroll
    for (int nt = 0; nt < 8; ++nt)
        #pragma unroll
        for (int r = 0; r < 4; ++r) {
            float d = y[nt][r] - mean1;
            s2 += d * d;
        }
    s2 += __shfl_xor(s2, 16);
    s2 += __shfl_xor(s2, 32);
    const float rstd1 = 1.f / sqrtf(s2 * (1.f / 128.f) + 1e-5f);
    #pragma unroll
    for (int nt = 0; nt < 8; ++nt) {
        const int nb = nt * 16 + quad * 4;
        float4 g4 = *(const float4*)&g1[nb];
        float4 be4 = *(const float4*)&be1[nb];
        #pragma unroll
        for (int r = 0; r < 4; ++r)
            y[nt][r] = (y[nt][r] - mean1) * rstd1 * ((const float*)&g4)[r] + ((const float*)&be4)[r];
        uint2 w2;
        w2.x = permpack(y[nt][1], y[nt][0]);
        w2.y = permpack(y[nt][3], y[nt][2]);
        *(uint2*)&Ys[lrow * 136 + nb] = w2;     // wave-private row
    }

    // ---- FFN1: h = elu(y @ W1^T + b1) ----
    f32x4 acc1[4];
    #pragma unroll
    for (int nt = 0; nt < 4; ++nt) acc1[nt] = (f32x4){0.f, 0.f, 0.f, 0.f};
    const ushort_t* yp = &Ys[lrow * 136 + quad * 8];
    const ushort_t* w1p = W1 + (size_t)l16 * EE + quad * 8;
    #pragma unroll
    for (int k0 = 0; k0 < 128; k0 += 32) {
        bf16x8 a = *(const bf16x8*)(yp + k0);
        #pragma unroll
        for (int nt = 0; nt < 4; ++nt) {
            bf16x8 wf = *(const bf16x8*)(w1p + (size_t)nt * 16 * EE + k0);
            acc1[nt] = __builtin_amdgcn_mfma_f32_16x16x32_bf16(wf, a, acc1[nt], 0, 0, 0);
        }
    }
    #pragma unroll
    for (int nt = 0; nt < 4; ++nt) {
        const int ib = nt * 16 + quad * 4;
        float4 b4 = *(const float4*)&b1[ib];
        float hv[4];
        #pragma unroll
        for (int r = 0; r < 4; ++r) {
            float u = acc1[nt][r] + ((const float*)&b4)[r];
            hv[r] = u > 0.f ? u : expm1f(u);
        }
        uint2 w2;
        w2.x = permpack(hv[1], hv[0]);
        w2.y = permpack(hv[3], hv[2]);
        *(uint2*)&Hs[lrow * 72 + ib] = w2;      // wave-private row
    }

    // ---- FFN2: ffn_out = h @ W2^T ----
    f32x4 acc2[8];
    #pragma unroll
    for (int nt = 0; nt < 8; ++nt) acc2[nt] = (f32x4){0.f, 0.f, 0.f, 0.f};
    const ushort_t* hp = &Hs[lrow * 72 + quad * 8];
    const ushort_t* w2p = W2 + (size_t)l16 * II + quad * 8;
    #pragma unroll
    for (int k0 = 0; k0 < 64; k0 += 32) {
        bf16x8 hf = *(const bf16x8*)(hp + k0);
        #pragma unroll
        for (int nt = 0; nt < 8; ++nt) {
            bf16x8 wf = *(const bf16x8*)(w2p + (size_t)nt * 16 * II + k0);
            acc2[nt] = __builtin_amdgcn_mfma_f32_16x16x32_bf16(wf, hf, acc2[nt], 0, 0, 0);
        }
    }

    // ---- LN2 ----
    float v[8][4];
    float s3 = 0.f;
    #pragma unroll
    for (int nt = 0; nt < 8; ++nt) {
        const int nb = nt * 16 + quad * 4;
        float4 b4 = *(const float4*)&b2[nb];
        #pragma unroll
        for (int r = 0; r < 4; ++r) {
            v[nt][r] = acc2[nt][r] + ((const float*)&b4)[r] + y[nt][r];
            s3 += v[nt][r];
        }
    }
    s3 += __shfl_xor(s3, 16);
    s3 += __shfl_xor(s3, 32);
    const float mean2 = s3 * (1.f / 128.f);
    float s4 = 0.f;
    #pragma unroll
    for (int nt = 0; nt < 8; ++nt)
        #pragma unroll
        for (int r = 0; r < 4; ++r) {
            float d = v[nt][r] - mean2;
            s4 += d * d;
        }
    s4 += __shfl_xor(s4, 16);
    s4 += __shfl_xor(s4, 32);
    const float rstd2 = 1.f / sqrtf(s4 * (1.f / 128.f) + 1e-5f);
    #pragma unroll
    for (int nt = 0; nt < 8; ++nt) {
        const int nb = nt * 16 + quad * 4;
        float4 g4 = *(const float4*)&g2[nb];
        float4 be4 = *(const float4*)&be2[nb];
        float out4[4];
        #pragma unroll
        for (int r = 0; r < 4; ++r)
            out4[r] = (v[nt][r] - mean2) * rstd2 * ((const float*)&g4)[r] + ((const float*)&be4)[r];
        float4 f4 = {out4[0], out4[1], out4[2], out4[3]};
        *(float4*)&seq[(size_t)m * EE + nb] = f4;
        uint2 w2;
        w2.x = permpack(out4[1], out4[0]);
        w2.y = permpack(out4[3], out4[2]);
        *(uint2*)&seq_bf[(size_t)m * EE + nb] = w2;
    }
}

// ---------------------------------------------------------------------------
// Final projection, split-K MFMA (unchanged).
// ---------------------------------------------------------------------------
#define PKC 192
#define PNBLK (KOUT / PKC)   // 512
__global__ __launch_bounds__(256) void out_gemm3(
    const ushort_t* __restrict__ seqbf, const float* __restrict__ out_w,
    float* __restrict__ part)
{
    const int t = threadIdx.x;
    const int wave = t >> 6, lane = t & 63;
    const int quad = lane >> 4, l16 = lane & 15;
    const size_t k0 = (size_t)blockIdx.x * PKC;
    const int n0 = wave * 32;

    f32x4 acc[2][2];
    #pragma unroll
    for (int mt = 0; mt < 2; ++mt)
        #pragma unroll
        for (int nt = 0; nt < 2; ++nt)
            acc[mt][nt] = (f32x4){0.f, 0.f, 0.f, 0.f};

    const ushort_t* a0p = seqbf + (size_t)l16 * KOUT + k0 + quad * 8;
    const ushort_t* a1p = a0p + (size_t)16 * KOUT;
    const float* w0p = out_w + (size_t)(n0 + l16) * KOUT + k0 + quad * 8;
    const float* w1p = w0p + (size_t)16 * KOUT;

    #pragma unroll
    for (int ks = 0; ks < PKC; ks += 32) {
        bf16x8 a0 = *(const bf16x8*)(a0p + ks);
        bf16x8 a1 = *(const bf16x8*)(a1p + ks);
        float4 wa0 = *(const float4*)(w0p + ks);
        float4 wa1 = *(const float4*)(w0p + ks + 4);
        float4 wb0 = *(const float4*)(w1p + ks);
        float4 wb1 = *(const float4*)(w1p + ks + 4);
        u32x4 b0, b1;
        b0[0] = permpack(wa0.y, wa0.x); b0[1] = permpack(wa0.w, wa0.z);
        b0[2] = permpack(wa1.y, wa1.x); b0[3] = permpack(wa1.w, wa1.z);
        b1[0] = permpack(wb0.y, wb0.x); b1[1] = permpack(wb0.w, wb0.z);
        b1[2] = permpack(wb1.y, wb1.x); b1[3] = permpack(wb1.w, wb1.z);
        bf16x8 bf0 = __builtin_bit_cast(bf16x8, b0);
        bf16x8 bf1 = __builtin_bit_cast(bf16x8, b1);
        acc[0][0] = __builtin_amdgcn_mfma_f32_16x16x32_bf16(a0, bf0, acc[0][0], 0, 0, 0);
        acc[1][0] = __builtin_amdgcn_mfma_f32_16x16x32_bf16(a1, bf0, acc[1][0], 0, 0, 0);
        acc[0][1] = __builtin_amdgcn_mfma_f32_16x16x32_bf16(a0, bf1, acc[0][1], 0, 0, 0);
        acc[1][1] = __builtin_amdgcn_mfma_f32_16x16x32_bf16(a1, bf1, acc[1][1], 0, 0, 0);
    }

    float* pb = part + (size_t)blockIdx.x * (32 * 128);
    #pragma unroll
    for (int mt = 0; mt < 2; ++mt)
        #pragma unroll
        for (int nt = 0; nt < 2; ++nt)
            #pragma unroll
            for (int r = 0; r < 4; ++r)
                pb[(mt * 16 + quad * 4 + r) * 128 + n0 + nt * 16 + l16] = acc[mt][nt][r];
}

__global__ __launch_bounds__(256) void out_reduce(
    const float* __restrict__ part, const float* __restrict__ out_b,
    float* __restrict__ out)
{
    const int i = blockIdx.x * 256 + threadIdx.x;
    const float* p = part + i;
    float s0 = 0.f, s1 = 0.f, s2 = 0.f, s3 = 0.f;
    for (int blk = 0; blk < PNBLK; blk += 4) {
        s0 += p[(size_t)blk * 4096];
        s1 += p[(size_t)(blk + 1) * 4096];
        s2 += p[(size_t)(blk + 2) * 4096];
        s3 += p[(size_t)(blk + 3) * 4096];
    }
    out[i] = out_b[i & (OUTN - 1)] + ((s0 + s1) + (s2 + s3));
}

// ---------------------------------------------------------------------------
extern "C" void kernel_launch(void* const* d_in, const int* in_sizes, int n_in,
                              void* d_out, int out_size, void* d_ws, size_t ws_size,
                              hipStream_t stream)
{
    const float* x          = (const float*)d_in[0];
    const float* prototypes = (const float*)d_in[1];
    const float* emb_w      = (const float*)d_in[2];
    const float* emb_b      = (const float*)d_in[3];
    const float* proj_w     = (const float*)d_in[4];
    const float* proj_b     = (const float*)d_in[5];
    const float* in_proj_w  = (const float*)d_in[6];
    const float* in_proj_b  = (const float*)d_in[7];
    const float* out_proj_w = (const float*)d_in[8];
    const float* out_proj_b = (const float*)d_in[9];
    const float* ln1_s      = (const float*)d_in[10];
    const float* ln1_b      = (const float*)d_in[11];
    const float* ffn_w1     = (const float*)d_in[12];
    const float* ffn_b1     = (const float*)d_in[13];
    const float* ffn_w2     = (const float*)d_in[14];
    const float* ffn_b2     = (const float*)d_in[15];
    const float* ln2_s      = (const float*)d_in[16];
    const float* ln2_b      = (const float*)d_in[17];
    const float* out_w      = (const float*)d_in[18];
    const float* out_b      = (const float*)d_in[19];
    float* out = (float*)d_out;
    char* base = (char*)d_ws;

    float*    seq    = (float*)base;                        // 12,582,912
    float*    tmp    = (float*)(base + 12582912);           // 12,582,912 (= part)
    ushort_t* seq_bf = (ushort_t*)(base + 25165824);        //  6,291,456
    ushort_t* qkv_bf = (ushort_t*)(base + 31457280);        // 18,874,368
    ushort_t* ctx_bf = (ushort_t*)(base + 50331648);        //  6,291,456
    ushort_t* w_bf   = (ushort_t*)(base + 56623104);        //    327,680
    float*    part   = tmp;
    (void)ws_size;

    ushort_t* w_in  = w_bf;            // [2][384][128]
    ushort_t* w_out = w_bf + 98304;    // [2][128][128]
    ushort_t* w_f1  = w_bf + 131072;   // [2][64][128]
    ushort_t* w_f2  = w_bf + 147456;   // [2][128][64]

    cast_all_kernel<<<(163840 + 255) / 256, 256, 0, stream>>>(
        in_proj_w, 98304, out_proj_w, 32768, ffn_w1, 16384, ffn_w2, 16384,
        w_in, w_out, w_f1, w_f2);

    embed_kernel<<<ROWS, 128, 0, stream>>>(x, prototypes, emb_w, emb_b,
                                           proj_w, proj_b, seq, seq_bf);

    for (int l = 0; l < 2; ++l) {
        // qkv = seq @ Wqkv^T + b -> bf16 [24576, 384], Q cols pre-scaled 0.25
        gemm_direct<<<dim3(6, 192), 256, 0, stream>>>(
            seq_bf, w_in + (size_t)l * 49152, in_proj_b + l * 384,
            qkv_bf, ROWS, 384, 128, 2 | 4);
        attention_mfma<<<dim3(BB * HH, 3), 512, 0, stream>>>(qkv_bf, ctx_bf);
        // whole layer tail in one kernel (out-proj + LN1 + FFN + LN2)
        layer_tail<<<ROWS / 64, 256, 0, stream>>>(
            ctx_bf, w_out + (size_t)l * 16384, out_proj_b + l * 128,
            w_f1 + (size_t)l * 8192, ffn_b1 + l * II,
            w_f2 + (size_t)l * 8192, ffn_b2 + l * EE,
            ln1_s + l * EE, ln1_b + l * EE, ln2_s + l * EE, ln2_b + l * EE,
            seq, seq_bf);
    }

    out_gemm3<<<PNBLK, 256, 0, stream>>>(seq_bf, out_w, part);
    out_reduce<<<BB * OUTN / 256, 256, 0, stream>>>(part, out_b, out);
}

// Round 11
// 344.596 us; speedup vs baseline: 1.0392x; 1.0004x over previous
//
#include <hip/hip_runtime.h>
#include <hip/hip_bf16.h>
#include <math.h>

typedef unsigned short ushort_t;
typedef unsigned int uint_t;

// Problem constants
#define BB 32
#define PP 6
#define DD 96
#define EE 128
#define HH 8
#define II 64
#define KK 32
#define LSEQ 768            // N*D
#define ROWS (BB * LSEQ)    // 24576 token rows
#define OUTN 128
#define KOUT (LSEQ * EE)    // 98304

using bf16x8 = __attribute__((ext_vector_type(8))) short;
using bf16x4 = __attribute__((ext_vector_type(4))) short;
using f32x4  = __attribute__((ext_vector_type(4))) float;
using u32x4  = __attribute__((ext_vector_type(4))) uint_t;

__device__ __forceinline__ ushort_t f2b(float f) {
    __hip_bfloat16 h = __float2bfloat16(f);
    return *reinterpret_cast<ushort_t*>(&h);
}
// pack two fp32 -> (bf16(hi)<<16)|bf16(lo) by TRUNCATION: one v_perm_b32.
__device__ __forceinline__ uint_t permpack(float hi, float lo) {
    return __builtin_amdgcn_perm(__builtin_bit_cast(uint_t, hi),
                                 __builtin_bit_cast(uint_t, lo), 0x07060302u);
}

// ---------------------------------------------------------------------------
// Cast fp32 -> bf16, all four weight tensors in one launch.
// ---------------------------------------------------------------------------
__global__ void cast_all_kernel(
    const float* __restrict__ s0, int n0, const float* __restrict__ s1, int n1,
    const float* __restrict__ s2, int n2, const float* __restrict__ s3, int n3,
    ushort_t* __restrict__ d0, ushort_t* __restrict__ d1,
    ushort_t* __restrict__ d2, ushort_t* __restrict__ d3)
{
    int i = blockIdx.x * 256 + threadIdx.x;
    if (i < n0) { d0[i] = f2b(s0[i]); return; }
    i -= n0;
    if (i < n1) { d1[i] = f2b(s1[i]); return; }
    i -= n1;
    if (i < n2) { d2[i] = f2b(s2[i]); return; }
    i -= n2;
    if (i < n3) { d3[i] = f2b(s3[i]); }
}

// ---------------------------------------------------------------------------
// Embed (unchanged).
// ---------------------------------------------------------------------------
__global__ __launch_bounds__(128) void embed_kernel(
    const float* __restrict__ x, const float* __restrict__ prot,
    const float* __restrict__ emb_w, const float* __restrict__ emb_b,
    const float* __restrict__ proj_w, const float* __restrict__ proj_b,
    float* __restrict__ seq, ushort_t* __restrict__ seq_bf)
{
    const int r = blockIdx.x;
    const int t = threadIdx.x;
    __shared__ float xrow[PP];
    __shared__ float sel[PP];

    if (t < PP) xrow[t] = x[r * PP + t];
    __syncthreads();

    float nx = 0.f;
    #pragma unroll
    for (int p = 0; p < PP; ++p) nx += xrow[p] * xrow[p];
    const float xinv = 1.f / fmaxf(sqrtf(nx), 1e-12f);

    const int d = r % DD;
    if (t < KK) {
        const float* pr = prot + (d * KK + t) * PP;
        float pp[PP];
        float np2 = 0.f;
        #pragma unroll
        for (int p = 0; p < PP; ++p) { pp[p] = pr[p]; np2 += pp[p] * pp[p]; }
        const float pinv = 1.f / fmaxf(sqrtf(np2), 1e-12f);
        float dot = 0.f;
        #pragma unroll
        for (int p = 0; p < PP; ++p) dot += xrow[p] * pp[p];
        float sim = dot * xinv * pinv;
        int k = t;
        #pragma unroll
        for (int off = 16; off; off >>= 1) {
            float osim = __shfl_down(sim, off);
            int   ok   = __shfl_down(k, off);
            if (osim > sim || (osim == sim && ok < k)) { sim = osim; k = ok; }
        }
        k = __shfl(k, 0);
        if (t == k) {
            #pragma unroll
            for (int p = 0; p < PP; ++p) sel[p] = pp[p] * pinv;
        }
    }
    __syncthreads();

    float acc = emb_b[t] + proj_b[t];
    #pragma unroll
    for (int p = 0; p < PP; ++p) acc = fmaf(xrow[p], emb_w[t * PP + p], acc);
    #pragma unroll
    for (int p = 0; p < PP; ++p) acc = fmaf(sel[p], proj_w[t * PP + p], acc);

    const int lpos = r % LSEQ;
    const float twoj = (float)((t >> 1) * 2);
    const float div = __expf(twoj * (-9.210340371976184f / 128.0f));
    const float ang = (float)lpos * div;
    const float pe = (t & 1) ? cosf(ang) : sinf(ang);
    const float v = acc + pe;
    seq[(size_t)r * EE + t] = v;
    seq_bf[(size_t)r * EE + t] = f2b(v);
}

// ---------------------------------------------------------------------------
// Direct-activation MFMA GEMM (swapped operands) — qkv projection.
// flags: 1 = ELU; 2 = bf16 out; 4 = scale cols n<128 by 0.25*log2(e)
//        (Q pre-scale, folded so attention can use native exp2).
// ---------------------------------------------------------------------------
#define QSCALE 0.36067376022224085f   // 0.25 * log2(e)
__global__ __launch_bounds__(256) void gemm_direct(
    const ushort_t* __restrict__ A, const ushort_t* __restrict__ W,
    const float* __restrict__ bias, void* __restrict__ Cout,
    int M, int N, int K, int flags)
{
    __shared__ ushort_t Ws[64 * 136];
    const int t = threadIdx.x;
    const int wave = t >> 6, lane = t & 63;
    const int quad = lane >> 4, l16 = lane & 15;
    const int m0 = blockIdx.y * 128, n0 = blockIdx.x * 64;
    const int kp = K + 8;
    const int ak8 = K >> 3;

    for (int c = t; c < 64 * ak8; c += 256) {
        int row = c / ak8, col = c - row * ak8;
        *(bf16x8*)&Ws[row * kp + col * 8] =
            *(const bf16x8*)&W[(size_t)(n0 + row) * K + col * 8];
    }
    __syncthreads();

    f32x4 acc[2][4];
    #pragma unroll
    for (int s = 0; s < 2; ++s)
        #pragma unroll
        for (int nt = 0; nt < 4; ++nt)
            acc[s][nt] = (f32x4){0.f, 0.f, 0.f, 0.f};

    const ushort_t* a0p = A + (size_t)(m0 + wave * 32 + l16) * K + quad * 8;
    const ushort_t* a1p = a0p + (size_t)16 * K;
    const ushort_t* wp  = &Ws[l16 * kp + quad * 8];

    for (int k0 = 0; k0 < K; k0 += 32) {
        bf16x8 a0 = *(const bf16x8*)(a0p + k0);
        bf16x8 a1 = *(const bf16x8*)(a1p + k0);
        #pragma unroll
        for (int nt = 0; nt < 4; ++nt) {
            bf16x8 wf = *(const bf16x8*)(wp + nt * 16 * kp + k0);
            acc[0][nt] = __builtin_amdgcn_mfma_f32_16x16x32_bf16(wf, a0, acc[0][nt], 0, 0, 0);
            acc[1][nt] = __builtin_amdgcn_mfma_f32_16x16x32_bf16(wf, a1, acc[1][nt], 0, 0, 0);
        }
    }

    #pragma unroll
    for (int s = 0; s < 2; ++s) {
        const int m = m0 + wave * 32 + s * 16 + l16;
        #pragma unroll
        for (int nt = 0; nt < 4; ++nt) {
            const int nb = n0 + nt * 16 + quad * 4;
            float4 b4 = *(const float4*)&bias[nb];
            float v[4];
            #pragma unroll
            for (int r = 0; r < 4; ++r) {
                v[r] = acc[s][nt][r] + ((const float*)&b4)[r];
                if (flags & 1) v[r] = v[r] > 0.f ? v[r] : expm1f(v[r]);
            }
            if ((flags & 4) && nb < EE) {
                #pragma unroll
                for (int r = 0; r < 4; ++r) v[r] *= QSCALE;
            }
            if (flags & 2) {
                uint2 w2;
                w2.x = permpack(v[1], v[0]);
                w2.y = permpack(v[3], v[2]);
                *(uint2*)&((ushort_t*)Cout)[(size_t)m * N + nb] = w2;
            } else {
                float4 f4 = {v[0], v[1], v[2], v[3]};
                *(float4*)&((float*)Cout)[(size_t)m * N + nb] = f4;
            }
        }
    }
}

// ---------------------------------------------------------------------------
// MFMA flash attention v8: 3 q-strips per wave (3 independent S->exp->PV
// chains for ILP), grid (256 bh, 2 qchunks of 384) = 512 blocks = exactly
// 2/CU. Plain loads + #pragma unroll 2 (compiler hoists next iter's K/V
// loads). exp2f (Q pre-scaled by 0.25*log2e in the qkv epilogue) — saves
// the per-exp v_mul. VTS=796 (16-bank-distinct rows). No VGPR cap.
// ---------------------------------------------------------------------------
#define VTS 796
__global__ __launch_bounds__(512) void attention_mfma(
    const ushort_t* __restrict__ qkv, ushort_t* __restrict__ ctx)
{
    __shared__ ushort_t Vt[16 * VTS];

    const int bh = blockIdx.x;
    const int b = bh & 31, h = bh >> 5;     // XCD swizzle: id%8 == b%8
    const int qb = blockIdx.y * 384;
    const int t = threadIdx.x;
    const int wave = t >> 6, lane = t & 63;
    const int quad = lane >> 4, l16 = lane & 15;
    const size_t bbase = (size_t)b * LSEQ * 384;
    const int hoff = h * 16;

    // ---- stage V transposed ----
    for (int idx = t; idx < 1536; idx += 512) {
        int row = idx >> 1, half = idx & 1;
        bf16x8 v = *(const bf16x8*)&qkv[bbase + (size_t)row * 384 + 2 * EE + hoff + half * 8];
        #pragma unroll
        for (int j = 0; j < 8; ++j)
            Vt[(half * 8 + j) * VTS + row] = (ushort_t)v[j];
    }

    // ---- Q fragments: 3 strips of 16 rows per wave ----
    bf16x4 qf[3];
    #pragma unroll
    for (int s = 0; s < 3; ++s) {
        int row = qb + wave * 48 + s * 16 + l16;
        qf[s] = *(const bf16x4*)&qkv[bbase + (size_t)row * 384 + hoff + quad * 4];
    }
    __syncthreads();

    f32x4 oacc[3];
    #pragma unroll
    for (int s = 0; s < 3; ++s) oacc[s] = (f32x4){0.f, 0.f, 0.f, 0.f};
    float lsum[3] = {0.f, 0.f, 0.f};
    const f32x4 zero4 = (f32x4){0.f, 0.f, 0.f, 0.f};

    const ushort_t* kbase = qkv + bbase + EE + hoff + quad * 4 + (size_t)l16 * 384;

    #pragma unroll 2
    for (int c = 0; c < 48; ++c) {
        bf16x4 kf = *(const bf16x4*)&kbase[(size_t)c * 16 * 384];
        bf16x4 vf = *(const bf16x4*)&Vt[l16 * VTS + c * 16 + quad * 4];

        #pragma unroll
        for (int s = 0; s < 3; ++s) {
            f32x4 sv = __builtin_amdgcn_mfma_f32_16x16x16bf16_1k(kf, qf[s], zero4, 0, 0, 0);
            float e0 = exp2f(sv[0]), e1 = exp2f(sv[1]);
            float e2 = exp2f(sv[2]), e3 = exp2f(sv[3]);
            lsum[s] += (e0 + e1) + (e2 + e3);
            uint2 pu;
            pu.x = permpack(e1, e0);
            pu.y = permpack(e3, e2);
            bf16x4 pf = __builtin_bit_cast(bf16x4, pu);
            oacc[s] = __builtin_amdgcn_mfma_f32_16x16x16bf16_1k(vf, pf, oacc[s], 0, 0, 0);
        }
    }

    #pragma unroll
    for (int s = 0; s < 3; ++s) {
        float tot = lsum[s];
        tot += __shfl_xor(tot, 16);
        tot += __shfl_xor(tot, 32);
        const float inv = 1.f / tot;
        const int q = qb + wave * 48 + s * 16 + l16;
        uint2 w2;
        w2.x = permpack(oacc[s][1] * inv, oacc[s][0] * inv);
        w2.y = permpack(oacc[s][3] * inv, oacc[s][2] * inv);
        *(uint2*)&ctx[((size_t)(b * LSEQ + q)) * EE + hoff + quad * 4] = w2;
    }
}

// ---------------------------------------------------------------------------
// Fused layer tail: seq = LN2(y + FFN(y)), y = LN1(seq + ctx@Wout^T + bout).
// Now 128-thread blocks x 32 rows -> grid 768 = exactly 3 blocks/CU
// (round-10: 384 blocks on 256 CUs left half the CUs with 2 serial rounds).
// ---------------------------------------------------------------------------
__global__ __launch_bounds__(128) void layer_tail(
    const ushort_t* __restrict__ ctx, const ushort_t* __restrict__ Wout,
    const float* __restrict__ bout,
    const ushort_t* __restrict__ W1, const float* __restrict__ b1,
    const ushort_t* __restrict__ W2, const float* __restrict__ b2,
    const float* __restrict__ g1, const float* __restrict__ be1,
    const float* __restrict__ g2, const float* __restrict__ be2,
    float* __restrict__ seq, ushort_t* __restrict__ seq_bf)
{
    __shared__ ushort_t Ys[32 * 136];
    __shared__ ushort_t Hs[32 * 72];
    const int t = threadIdx.x;
    const int wave = t >> 6, lane = t & 63;
    const int quad = lane >> 4, l16 = lane & 15;
    const int lrow = wave * 16 + l16;          // 0..31
    const int m = blockIdx.x * 32 + lrow;

    // ---- out-proj GEMM: attn_out = ctx @ Wout^T ----
    f32x4 acc[8];
    #pragma unroll
    for (int nt = 0; nt < 8; ++nt) acc[nt] = (f32x4){0.f, 0.f, 0.f, 0.f};
    const ushort_t* ap = ctx + (size_t)m * EE + quad * 8;
    const ushort_t* wp = Wout + (size_t)l16 * EE + quad * 8;
    #pragma unroll
    for (int k0 = 0; k0 < 128; k0 += 32) {
        bf16x8 a = *(const bf16x8*)(ap + k0);
        #pragma unroll
        for (int nt = 0; nt < 8; ++nt) {
            bf16x8 wf = *(const bf16x8*)(wp + (size_t)nt * 16 * EE + k0);
            acc[nt] = __builtin_amdgcn_mfma_f32_16x16x32_bf16(wf, a, acc[nt], 0, 0, 0);
        }
    }

    // ---- LN1 ----
    float y[8][4];
    float s = 0.f;
    #pragma unroll
    for (int nt = 0; nt < 8; ++nt) {
        const int nb = nt * 16 + quad * 4;
        float4 b4 = *(const float4*)&bout[nb];
        float4 r4 = *(const float4*)&seq[(size_t)m * EE + nb];
        #pragma unroll
        for (int r = 0; r < 4; ++r) {
            y[nt][r] = acc[nt][r] + ((const float*)&b4)[r] + ((const float*)&r4)[r];
            s += y[nt][r];
        }
    }
    s += __shfl_xor(s, 16);
    s += __shfl_xor(s, 32);
    const float mean1 = s * (1.f / 128.f);
    float s2 = 0.f;
    #pragma unroll
    for (int nt = 0; nt < 8; ++nt)
        #pragma unroll
        for (int r = 0; r < 4; ++r) {
            float d = y[nt][r] - mean1;
            s2 += d * d;
        }
    s2 += __shfl_xor(s2, 16);
    s2 += __shfl_xor(s2, 32);
    const float rstd1 = 1.f / sqrtf(s2 * (1.f / 128.f) + 1e-5f);
    #pragma unroll
    for (int nt = 0; nt < 8; ++nt) {
        const int nb = nt * 16 + quad * 4;
        float4 g4 = *(const float4*)&g1[nb];
        float4 be4 = *(const float4*)&be1[nb];
        #pragma unroll
        for (int r = 0; r < 4; ++r)
            y[nt][r] = (y[nt][r] - mean1) * rstd1 * ((const float*)&g4)[r] + ((const float*)&be4)[r];
        uint2 w2;
        w2.x = permpack(y[nt][1], y[nt][0]);
        w2.y = permpack(y[nt][3], y[nt][2]);
        *(uint2*)&Ys[lrow * 136 + nb] = w2;     // wave-private row
    }

    // ---- FFN1: h = elu(y @ W1^T + b1) ----
    f32x4 acc1[4];
    #pragma unroll
    for (int nt = 0; nt < 4; ++nt) acc1[nt] = (f32x4){0.f, 0.f, 0.f, 0.f};
    const ushort_t* yp = &Ys[lrow * 136 + quad * 8];
    const ushort_t* w1p = W1 + (size_t)l16 * EE + quad * 8;
    #pragma unroll
    for (int k0 = 0; k0 < 128; k0 += 32) {
        bf16x8 a = *(const bf16x8*)(yp + k0);
        #pragma unroll
        for (int nt = 0; nt < 4; ++nt) {
            bf16x8 wf = *(const bf16x8*)(w1p + (size_t)nt * 16 * EE + k0);
            acc1[nt] = __builtin_amdgcn_mfma_f32_16x16x32_bf16(wf, a, acc1[nt], 0, 0, 0);
        }
    }
    #pragma unroll
    for (int nt = 0; nt < 4; ++nt) {
        const int ib = nt * 16 + quad * 4;
        float4 b4 = *(const float4*)&b1[ib];
        float hv[4];
        #pragma unroll
        for (int r = 0; r < 4; ++r) {
            float u = acc1[nt][r] + ((const float*)&b4)[r];
            hv[r] = u > 0.f ? u : expm1f(u);
        }
        uint2 w2;
        w2.x = permpack(hv[1], hv[0]);
        w2.y = permpack(hv[3], hv[2]);
        *(uint2*)&Hs[lrow * 72 + ib] = w2;      // wave-private row
    }

    // ---- FFN2: ffn_out = h @ W2^T ----
    f32x4 acc2[8];
    #pragma unroll
    for (int nt = 0; nt < 8; ++nt) acc2[nt] = (f32x4){0.f, 0.f, 0.f, 0.f};
    const ushort_t* hp = &Hs[lrow * 72 + quad * 8];
    const ushort_t* w2p = W2 + (size_t)l16 * II + quad * 8;
    #pragma unroll
    for (int k0 = 0; k0 < 64; k0 += 32) {
        bf16x8 hf = *(const bf16x8*)(hp + k0);
        #pragma unroll
        for (int nt = 0; nt < 8; ++nt) {
            bf16x8 wf = *(const bf16x8*)(w2p + (size_t)nt * 16 * II + k0);
            acc2[nt] = __builtin_amdgcn_mfma_f32_16x16x32_bf16(wf, hf, acc2[nt], 0, 0, 0);
        }
    }

    // ---- LN2 ----
    float v[8][4];
    float s3 = 0.f;
    #pragma unroll
    for (int nt = 0; nt < 8; ++nt) {
        const int nb = nt * 16 + quad * 4;
        float4 b4 = *(const float4*)&b2[nb];
        #pragma unroll
        for (int r = 0; r < 4; ++r) {
            v[nt][r] = acc2[nt][r] + ((const float*)&b4)[r] + y[nt][r];
            s3 += v[nt][r];
        }
    }
    s3 += __shfl_xor(s3, 16);
    s3 += __shfl_xor(s3, 32);
    const float mean2 = s3 * (1.f / 128.f);
    float s4 = 0.f;
    #pragma unroll
    for (int nt = 0; nt < 8; ++nt)
        #pragma unroll
        for (int r = 0; r < 4; ++r) {
            float d = v[nt][r] - mean2;
            s4 += d * d;
        }
    s4 += __shfl_xor(s4, 16);
    s4 += __shfl_xor(s4, 32);
    const float rstd2 = 1.f / sqrtf(s4 * (1.f / 128.f) + 1e-5f);
    #pragma unroll
    for (int nt = 0; nt < 8; ++nt) {
        const int nb = nt * 16 + quad * 4;
        float4 g4 = *(const float4*)&g2[nb];
        float4 be4 = *(const float4*)&be2[nb];
        float out4[4];
        #pragma unroll
        for (int r = 0; r < 4; ++r)
            out4[r] = (v[nt][r] - mean2) * rstd2 * ((const float*)&g4)[r] + ((const float*)&be4)[r];
        float4 f4 = {out4[0], out4[1], out4[2], out4[3]};
        *(float4*)&seq[(size_t)m * EE + nb] = f4;
        uint2 w2;
        w2.x = permpack(out4[1], out4[0]);
        w2.y = permpack(out4[3], out4[2]);
        *(uint2*)&seq_bf[(size_t)m * EE + nb] = w2;
    }
}

// ---------------------------------------------------------------------------
// Final projection, split-K MFMA (unchanged).
// ---------------------------------------------------------------------------
#define PKC 192
#define PNBLK (KOUT / PKC)   // 512
__global__ __launch_bounds__(256) void out_gemm3(
    const ushort_t* __restrict__ seqbf, const float* __restrict__ out_w,
    float* __restrict__ part)
{
    const int t = threadIdx.x;
    const int wave = t >> 6, lane = t & 63;
    const int quad = lane >> 4, l16 = lane & 15;
    const size_t k0 = (size_t)blockIdx.x * PKC;
    const int n0 = wave * 32;

    f32x4 acc[2][2];
    #pragma unroll
    for (int mt = 0; mt < 2; ++mt)
        #pragma unroll
        for (int nt = 0; nt < 2; ++nt)
            acc[mt][nt] = (f32x4){0.f, 0.f, 0.f, 0.f};

    const ushort_t* a0p = seqbf + (size_t)l16 * KOUT + k0 + quad * 8;
    const ushort_t* a1p = a0p + (size_t)16 * KOUT;
    const float* w0p = out_w + (size_t)(n0 + l16) * KOUT + k0 + quad * 8;
    const float* w1p = w0p + (size_t)16 * KOUT;

    #pragma unroll
    for (int ks = 0; ks < PKC; ks += 32) {
        bf16x8 a0 = *(const bf16x8*)(a0p + ks);
        bf16x8 a1 = *(const bf16x8*)(a1p + ks);
        float4 wa0 = *(const float4*)(w0p + ks);
        float4 wa1 = *(const float4*)(w0p + ks + 4);
        float4 wb0 = *(const float4*)(w1p + ks);
        float4 wb1 = *(const float4*)(w1p + ks + 4);
        u32x4 b0, b1;
        b0[0] = permpack(wa0.y, wa0.x); b0[1] = permpack(wa0.w, wa0.z);
        b0[2] = permpack(wa1.y, wa1.x); b0[3] = permpack(wa1.w, wa1.z);
        b1[0] = permpack(wb0.y, wb0.x); b1[1] = permpack(wb0.w, wb0.z);
        b1[2] = permpack(wb1.y, wb1.x); b1[3] = permpack(wb1.w, wb1.z);
        bf16x8 bf0 = __builtin_bit_cast(bf16x8, b0);
        bf16x8 bf1 = __builtin_bit_cast(bf16x8, b1);
        acc[0][0] = __builtin_amdgcn_mfma_f32_16x16x32_bf16(a0, bf0, acc[0][0], 0, 0, 0);
        acc[1][0] = __builtin_amdgcn_mfma_f32_16x16x32_bf16(a1, bf0, acc[1][0], 0, 0, 0);
        acc[0][1] = __builtin_amdgcn_mfma_f32_16x16x32_bf16(a0, bf1, acc[0][1], 0, 0, 0);
        acc[1][1] = __builtin_amdgcn_mfma_f32_16x16x32_bf16(a1, bf1, acc[1][1], 0, 0, 0);
    }

    float* pb = part + (size_t)blockIdx.x * (32 * 128);
    #pragma unroll
    for (int mt = 0; mt < 2; ++mt)
        #pragma unroll
        for (int nt = 0; nt < 2; ++nt)
            #pragma unroll
            for (int r = 0; r < 4; ++r)
                pb[(mt * 16 + quad * 4 + r) * 128 + n0 + nt * 16 + l16] = acc[mt][nt][r];
}

__global__ __launch_bounds__(256) void out_reduce(
    const float* __restrict__ part, const float* __restrict__ out_b,
    float* __restrict__ out)
{
    const int i = blockIdx.x * 256 + threadIdx.x;
    const float* p = part + i;
    float s0 = 0.f, s1 = 0.f, s2 = 0.f, s3 = 0.f;
    for (int blk = 0; blk < PNBLK; blk += 4) {
        s0 += p[(size_t)blk * 4096];
        s1 += p[(size_t)(blk + 1) * 4096];
        s2 += p[(size_t)(blk + 2) * 4096];
        s3 += p[(size_t)(blk + 3) * 4096];
    }
    out[i] = out_b[i & (OUTN - 1)] + ((s0 + s1) + (s2 + s3));
}

// ---------------------------------------------------------------------------
extern "C" void kernel_launch(void* const* d_in, const int* in_sizes, int n_in,
                              void* d_out, int out_size, void* d_ws, size_t ws_size,
                              hipStream_t stream)
{
    const float* x          = (const float*)d_in[0];
    const float* prototypes = (const float*)d_in[1];
    const float* emb_w      = (const float*)d_in[2];
    const float* emb_b      = (const float*)d_in[3];
    const float* proj_w     = (const float*)d_in[4];
    const float* proj_b     = (const float*)d_in[5];
    const float* in_proj_w  = (const float*)d_in[6];
    const float* in_proj_b  = (const float*)d_in[7];
    const float* out_proj_w = (const float*)d_in[8];
    const float* out_proj_b = (const float*)d_in[9];
    const float* ln1_s      = (const float*)d_in[10];
    const float* ln1_b      = (const float*)d_in[11];
    const float* ffn_w1     = (const float*)d_in[12];
    const float* ffn_b1     = (const float*)d_in[13];
    const float* ffn_w2     = (const float*)d_in[14];
    const float* ffn_b2     = (const float*)d_in[15];
    const float* ln2_s      = (const float*)d_in[16];
    const float* ln2_b      = (const float*)d_in[17];
    const float* out_w      = (const float*)d_in[18];
    const float* out_b      = (const float*)d_in[19];
    float* out = (float*)d_out;
    char* base = (char*)d_ws;

    float*    seq    = (float*)base;                        // 12,582,912
    float*    tmp    = (float*)(base + 12582912);           // 12,582,912 (= part)
    ushort_t* seq_bf = (ushort_t*)(base + 25165824);        //  6,291,456
    ushort_t* qkv_bf = (ushort_t*)(base + 31457280);        // 18,874,368
    ushort_t* ctx_bf = (ushort_t*)(base + 50331648);        //  6,291,456
    ushort_t* w_bf   = (ushort_t*)(base + 56623104);        //    327,680
    float*    part   = tmp;
    (void)ws_size;

    ushort_t* w_in  = w_bf;            // [2][384][128]
    ushort_t* w_out = w_bf + 98304;    // [2][128][128]
    ushort_t* w_f1  = w_bf + 131072;   // [2][64][128]
    ushort_t* w_f2  = w_bf + 147456;   // [2][128][64]

    cast_all_kernel<<<(163840 + 255) / 256, 256, 0, stream>>>(
        in_proj_w, 98304, out_proj_w, 32768, ffn_w1, 16384, ffn_w2, 16384,
        w_in, w_out, w_f1, w_f2);

    embed_kernel<<<ROWS, 128, 0, stream>>>(x, prototypes, emb_w, emb_b,
                                           proj_w, proj_b, seq, seq_bf);

    for (int l = 0; l < 2; ++l) {
        // qkv = seq @ Wqkv^T + b -> bf16 [24576, 384], Q pre-scaled 0.25*log2e
        gemm_direct<<<dim3(6, 192), 256, 0, stream>>>(
            seq_bf, w_in + (size_t)l * 49152, in_proj_b + l * 384,
            qkv_bf, ROWS, 384, 128, 2 | 4);
        attention_mfma<<<dim3(BB * HH, 2), 512, 0, stream>>>(qkv_bf, ctx_bf);
        // whole layer tail in one kernel (out-proj + LN1 + FFN + LN2)
        layer_tail<<<ROWS / 32, 128, 0, stream>>>(
            ctx_bf, w_out + (size_t)l * 16384, out_proj_b + l * 128,
            w_f1 + (size_t)l * 8192, ffn_b1 + l * II,
            w_f2 + (size_t)l * 8192, ffn_b2 + l * EE,
            ln1_s + l * EE, ln1_b + l * EE, ln2_s + l * EE, ln2_b + l * EE,
            seq, seq_bf);
    }

    out_gemm3<<<PNBLK, 256, 0, stream>>>(seq_bf, out_w, part);
    out_reduce<<<BB * OUTN / 256, 256, 0, stream>>>(part, out_b, out);
}